// Round 4
// baseline (246.572 us; speedup 1.0000x reference)
//
#include <hip/hip_runtime.h>
#include <stdint.h>

// MHA fused: B=4,T=2048,H=16,Dh=64,D=1024. fp32 in/out, bf16 MFMA internally.
// ws layout (bytes): [0,16M) x_bf16 (reused as ctx bf16 after QKV GEMM)
//                    [16M,24M) W^T bf16: wq|wk|wv|wo each 1024x1024 [n][k]
//                    [24M,40M) Q bf16 (B,H,T,Dh), pre-scaled by 0.125*log2(e)
//                    [40M,56M) K bf16 (B,H,T,Dh)
//                    [56M,72M) V^T bf16 (B,H,Dh,T), 4x4-interleaved j-blocks
// Total ws required: 75,497,472 bytes.
// R11: gemm_qkv keeps R10's verified 256^2/8-wave/128KB-dbuf structure but
// replaces __syncthreads (vmcnt(0) drain each tile = the ~1700cyc/tile stall)
// with a counted-vmcnt 2-barrier loop. R8's race is now understood: raw
// s_barrier has NO memory semantics in LLVM, so global_load_lds could hoist
// above it and land early, clobbering LDS mid-read. Fix: bracket every raw
// barrier with sched_barrier(0). vmcnt(8) retires exactly the current tile's
// 8 loads; the prefetch stays in flight across both barriers (never 0).

typedef unsigned short u16;
typedef __bf16 bf16x8 __attribute__((ext_vector_type(8)));
typedef short s16x4 __attribute__((ext_vector_type(4)));
typedef float f32x4 __attribute__((ext_vector_type(4)));

extern "C" __device__ float __ocml_native_exp2_f32(float);

__device__ __forceinline__ u16 f2bf(float f) {
  union { float f; unsigned u; } v; v.f = f;
  return (u16)((v.u + 0x7fffu + ((v.u >> 16) & 1u)) >> 16);
}

__device__ __forceinline__ void gl_lds16(const void* g, void* l) {
  // 16B per lane, LDS dest = wave-uniform base + lane*16
  __builtin_amdgcn_global_load_lds((__attribute__((address_space(1))) void*)g,
                                   (__attribute__((address_space(3))) void*)l,
                                   16, 0, 0);
}

__global__ __launch_bounds__(256) void conv_x_k(const float* __restrict__ x,
                                                u16* __restrict__ xb) {
  int i = (blockIdx.x * 256 + threadIdx.x) * 4;
  float4 v = *reinterpret_cast<const float4*>(x + i);
  ushort4 o;
  o.x = f2bf(v.x); o.y = f2bf(v.y); o.z = f2bf(v.z); o.w = f2bf(v.w);
  *reinterpret_cast<ushort4*>(xb + i) = o;
}

// transpose 1024x1024 fp32 [k][n] -> bf16 [n][k]; z selects wq/wk/wv/wo
__global__ __launch_bounds__(256) void conv_w_k(const float* __restrict__ w0,
                                                const float* __restrict__ w1,
                                                const float* __restrict__ w2,
                                                const float* __restrict__ w3,
                                                u16* __restrict__ dst) {
  const float* src = blockIdx.z == 0 ? w0 : blockIdx.z == 1 ? w1
                   : blockIdx.z == 2 ? w2 : w3;
  u16* d = dst + (size_t)blockIdx.z * 1024 * 1024;
  __shared__ float tile[32][33];
  int n0 = blockIdx.x * 32, k0 = blockIdx.y * 32;
  int tx = threadIdx.x & 31, ty = threadIdx.x >> 5;  // 32 x 8
  #pragma unroll
  for (int r = 0; r < 32; r += 8)
    tile[ty + r][tx] = src[(k0 + ty + r) * 1024 + n0 + tx];
  __syncthreads();
  #pragma unroll
  for (int r = 0; r < 32; r += 8)
    d[(n0 + ty + r) * 1024 + k0 + tx] = f2bf(tile[tx][ty + r]);
}

// GEMM staging layout: rows of 64 u16 (128B), 8 x 16B chunks/row,
// phys chunk = logical chunk ^ (row&7) -> frag ds_read_b128 is 2-way (free).
#define SWZ128(row, chunk) ((row) * 128 + ((((chunk) ^ ((row) & 7))) << 4))

// barrier bracketed by sched_barrier(0): raw s_barrier has no memory
// semantics in LLVM — without the brackets, global_load_lds can hoist
// above it and land early (the R8 race).
#define BARF do { __builtin_amdgcn_sched_barrier(0); \
                  __builtin_amdgcn_s_barrier(); \
                  __builtin_amdgcn_sched_barrier(0); } while (0)
#define VMW(n) do { asm volatile("s_waitcnt vmcnt(" #n ")" ::: "memory"); \
                    __builtin_amdgcn_sched_barrier(0); } while (0)

// ---- QKV GEMM: C(8192x1024 per proj) = xb @ W^T, epilogue scatters Q/K/V^T
// BM=BN=256, BK=64, 512 threads (8 waves, 2Mx4N, per-wave 128x64 output).
// LDS 128KB = 2 buffers x (A 32K | B 32K), alternating per K-tile.
// Per K-tile: issue next-tile stage (8 gl_lds16), vmcnt(8) retires current
// tile's loads only, barrier, ds_read frags + 64 MFMAs, lgkmcnt(0), barrier.
__global__ __launch_bounds__(512, 2) void gemm_qkv_k(const u16* __restrict__ A,
                                                     const u16* __restrict__ Wt,
                                                     u16* __restrict__ qw,
                                                     u16* __restrict__ kw,
                                                     u16* __restrict__ vtw) {
  __shared__ u16 SM[65536];  // 128 KB; V-epilogue reuses all of it
  const int tid = threadIdx.x;
  const int wave = tid >> 6, lane = tid & 63;
  const int quad = lane >> 4, l15 = lane & 15;
  const int m0 = blockIdx.x * 256;
  const int which = blockIdx.y >> 2;            // 0=Q 1=K 2=V
  const int n0 = (blockIdx.y & 3) * 256;
  const u16* Bt = Wt + which * (1024 * 1024);
  const int waveM = (wave >> 2) * 128, waveN = (wave & 3) * 64;

  const f32x4 fz = {0.f, 0.f, 0.f, 0.f};
  f32x4 acc[8][4];
  #pragma unroll
  for (int i = 0; i < 8; i++)
    #pragma unroll
    for (int j = 0; j < 4; j++) acc[i][j] = fz;

  // staging: per gl_lds16, wave covers rows {half*128 + i*64 + wave*8 + r8},
  // r8 = lane>>3; lane&7 = 16B chunk slot (phys chunk = logical ^ r8).
  const int lrow8 = lane >> 3, lchunk = lane & 7;
  const int gsw = (lchunk ^ lrow8) * 8;  // pre-swizzled source chunk, elems
  const u16* Ag = A + (m0 + wave * 8 + lrow8) * 1024 + gsw;
  const u16* Bg = Bt + (n0 + wave * 8 + lrow8) * 1024 + gsw;

  auto stage = [&](int o, int ktv) {
    #pragma unroll
    for (int half = 0; half < 2; half++)
      #pragma unroll
      for (int i = 0; i < 2; i++) {
        gl_lds16(Ag + (half * 128 + i * 64) * 1024 + ktv * 64,
                 (char*)SM + o + half * 16384 + i * 8192 + wave * 1024);
        gl_lds16(Bg + (half * 128 + i * 64) * 1024 + ktv * 64,
                 (char*)SM + o + 32768 + half * 16384 + i * 8192 + wave * 1024);
      }
  };

  stage(0, 0);  // prologue: tile 0 -> buffer 0

  for (int s = 0; s < 16; s++) {
    const int o = (s & 1) * 65536;   // byte offset of current buffer
    // stage s+1 into the other buffer (its readers, tile s-1, all crossed
    // the previous end-barrier); then retire exactly tile s's 8 loads.
    if (s < 15) { stage(65536 - o, s + 1); VMW(8); } else { VMW(0); }
    BARF;  // tile s visible to all waves; s+1's loads stay in flight

    bf16x8 bfr[4][2];
    #pragma unroll
    for (int nj = 0; nj < 4; nj++)
      #pragma unroll
      for (int kk = 0; kk < 2; kk++)
        bfr[nj][kk] = *reinterpret_cast<const bf16x8*>(
            (char*)SM + o + 32768 + SWZ128(waveN + nj * 16 + l15, kk * 4 + quad));

    #pragma unroll
    for (int g = 0; g < 2; g++) {
      bf16x8 af[4][2];
      #pragma unroll
      for (int mi = 0; mi < 4; mi++)
        #pragma unroll
        for (int kk = 0; kk < 2; kk++)
          af[mi][kk] = *reinterpret_cast<const bf16x8*>(
              (char*)SM + o + SWZ128(waveM + g * 64 + mi * 16 + l15, kk * 4 + quad));
      __builtin_amdgcn_s_setprio(1);
      #pragma unroll
      for (int kk = 0; kk < 2; kk++)
        #pragma unroll
        for (int mi = 0; mi < 4; mi++)
          #pragma unroll
          for (int nj = 0; nj < 4; nj++)
            acc[g * 4 + mi][nj] = __builtin_amdgcn_mfma_f32_16x16x32_bf16(
                af[mi][kk], bfr[nj][kk], acc[g * 4 + mi][nj], 0, 0, 0);
      __builtin_amdgcn_s_setprio(0);
    }
    asm volatile("s_waitcnt lgkmcnt(0)" ::: "memory");
    BARF;  // all waves done reading tile s -> its slot may be overwritten
  }

  if (which != 2) {  // Q/K: direct semi-coalesced u16 stores
    #pragma unroll
    for (int mi = 0; mi < 8; mi++) {
      #pragma unroll
      for (int r = 0; r < 4; r++) {
        int m = m0 + waveM + mi * 16 + quad * 4 + r;
        int b = m >> 11, t = m & 2047;
        #pragma unroll
        for (int nj = 0; nj < 4; nj++) {
          int n = n0 + waveN + nj * 16 + l15;
          int h = n >> 6, d = n & 63;
          float v = acc[mi][nj][r];
          // 0.125 * log2(e): attn exponentiates with native exp2
          if (which == 0) qw[((b * 16 + h) * 2048 + t) * 64 + d] = f2bf(v * 0.18033688f);
          else            kw[((b * 16 + h) * 2048 + t) * 64 + d] = f2bf(v);
        }
      }
    }
  } else {
    // V: transpose 256x256 tile in LDS (reuses all 128KB), then store
    // coalesced with 4x4-interleaved j-blocks (per-64-t permutation:
    // stored unit u' = quad*4+kc holds j-group g=(u'&3)*4+(u'>>2)).
    __syncthreads();  // all waves past final BARF; LDS reusable
    #pragma unroll
    for (int mi = 0; mi < 8; mi++)
      #pragma unroll
      for (int r = 0; r < 4; r++) {
        int ml = waveM + mi * 16 + quad * 4 + r;
        #pragma unroll
        for (int nj = 0; nj < 4; nj++) {
          int nl = waveN + nj * 16 + l15;
          // Ts[nl][ml]: 512B rows, 16B chunks of ml swizzled by nl&7
          int byte = nl * 512 + ((((ml >> 3) ^ (nl & 7))) << 4) + (ml & 7) * 2;
          *(u16*)((char*)SM + byte) = f2bf(acc[mi][nj][r]);
        }
      }
    __syncthreads();
    const int b = m0 >> 11, t0 = m0 & 2047;
    #pragma unroll
    for (int i = 0; i < 16; i++) {
      int cid = tid + 512 * i;        // 0..8191: (nl, 16B t-chunk)
      int nl = cid >> 5, tc = cid & 31;
      int jb = tc >> 3, cp = tc & 7;  // j-block within tile, chunk in block
      int gl = ((2 * cp) & 3) * 4 + ((2 * cp) >> 2);
      int gh = ((2 * cp + 1) & 3) * 4 + ((2 * cp + 1) >> 2);
      int ml0 = jb * 64 + gl * 4, ml1 = jb * 64 + gh * 4;
      s16x4 lo = *reinterpret_cast<const s16x4*>(
          (char*)SM + nl * 512 + (((ml0 >> 3) ^ (nl & 7)) << 4) + (ml0 & 7) * 2);
      s16x4 hi = *reinterpret_cast<const s16x4*>(
          (char*)SM + nl * 512 + (((ml1 >> 3) ^ (nl & 7)) << 4) + (ml1 & 7) * 2);
      union { s16x4 hh[2]; bf16x8 w; } uu;
      uu.hh[0] = lo; uu.hh[1] = hi;
      int n = n0 + nl;
      int h = n >> 6, d = n & 63;
      *reinterpret_cast<bf16x8*>(
          vtw + (((size_t)(b * 16 + h) * 64 + d) * 2048 + t0 + tc * 8)) = uu.w;
    }
  }
}

// ---- flash attention, causal. Br=Bc=64, one wave = 16 Q rows.
// P stays in registers (S^T C/D layout == 16x16x16 A-operand layout).
// native exp2 (log2e folded into Q scale); V tile 4x4-interleaved so V
// fragments are 8 conflict-free ds_read_b128 per iter.
__global__ __launch_bounds__(256) void attn_k(const u16* __restrict__ Q,
                                              const u16* __restrict__ K,
                                              const u16* __restrict__ Vt,
                                              u16* __restrict__ ctx) {
  __shared__ u16 Qs[64 * 64];
  __shared__ u16 Ks[2][64 * 64];
  __shared__ u16 Vs[2][64 * 64];    // V^T tile: [d][j-block interleaved]
  const int tid = threadIdx.x;
  const int wave = tid >> 6, lane = tid & 63;
  const int quad = lane >> 4, l15 = lane & 15;
  const int bh = blockIdx.x;
  const int qt = 31 - (int)blockIdx.y;          // big tiles dispatched first
  const int b = bh >> 4, h = bh & 15;

  const u16* Qg = Q + (bh * 2048 + qt * 64) * 64;
  const u16* Kg = K + bh * (2048 * 64);
  const u16* Vg = Vt + bh * (64 * 2048);

  const int lrow = tid >> 3;                       // 0..31
  const int lsw = ((tid & 7) ^ (lrow & 7)) * 8;    // swizzled chunk, elements

  // stage Q (swizzled): LDS slot tid*16, global chunk XORed by row&7
  gl_lds16(Qg + lrow * 64 + lsw, (char*)Qs + wave * 1024);
  gl_lds16(Qg + (32 + lrow) * 64 + lsw, (char*)Qs + wave * 1024 + 4096);
  // stage K/V tile 0
  {
    char* KsB = (char*)Ks[0] + wave * 1024;
    char* VsB = (char*)Vs[0] + wave * 1024;
    gl_lds16(Kg + lrow * 64 + lsw, KsB);
    gl_lds16(Kg + (32 + lrow) * 64 + lsw, KsB + 4096);
    gl_lds16(Vg + lrow * 2048 + lsw, VsB);
    gl_lds16(Vg + (32 + lrow) * 2048 + lsw, VsB + 4096);
  }

  const s16x4 ones4 = {(short)0x3F80, (short)0x3F80, (short)0x3F80, (short)0x3F80};
  const f32x4 fz = {0.f, 0.f, 0.f, 0.f};
  f32x4 accO[4];
  f32x4 accL = fz;
  #pragma unroll
  for (int dt = 0; dt < 4; dt++) accO[dt] = fz;
  bf16x8 qf[2];

  // swizzled fragment byte offset: row-major 64x64 u16, 16B chunk ^= row&7
  #define SWZB(row, chunk) ((row) * 128 + (((chunk) ^ ((row) & 7)) << 4))

  for (int j = 0; j <= qt; j++) {
    const int cur = j & 1;
    __syncthreads();  // drains vmcnt: tile j visible; buf cur^1 free to refill
    if (j < qt) {     // prefetch tile j+1 — stays in flight during compute j
      char* KsB = (char*)Ks[cur ^ 1] + wave * 1024;
      char* VsB = (char*)Vs[cur ^ 1] + wave * 1024;
      const int jr = (j + 1) * 64;
      gl_lds16(Kg + (jr + lrow) * 64 + lsw, KsB);
      gl_lds16(Kg + (jr + 32 + lrow) * 64 + lsw, KsB + 4096);
      gl_lds16(Vg + lrow * 2048 + jr + lsw, VsB);
      gl_lds16(Vg + (32 + lrow) * 2048 + jr + lsw, VsB + 4096);
    }
    if (j == 0) {
      #pragma unroll
      for (int kk = 0; kk < 2; kk++)
        qf[kk] = *reinterpret_cast<const bf16x8*>(
            (char*)Qs + SWZB(wave * 16 + l15, kk * 4 + quad));
    }

    // S^T tiles: mfma(A=kf, B=qf) -> lane holds S[q=l15][kcol=nt*16+quad*4+r]
    f32x4 s[4];
    #pragma unroll
    for (int nt = 0; nt < 4; nt++) s[nt] = fz;
    #pragma unroll
    for (int kk = 0; kk < 2; kk++)
      #pragma unroll
      for (int nt = 0; nt < 4; nt++) {
        bf16x8 kf = *reinterpret_cast<const bf16x8*>(
            (char*)Ks[cur] + SWZB(nt * 16 + l15, kk * 4 + quad));
        s[nt] = __builtin_amdgcn_mfma_f32_16x16x32_bf16(kf, qf[kk], s[nt], 0, 0, 0);
      }

    if (j == qt) {  // diagonal tile: mask kcol > qrow
      const int qrow = wave * 16 + l15;
      #pragma unroll
      for (int nt = 0; nt < 4; nt++)
        #pragma unroll
        for (int r = 0; r < 4; r++)
          if (nt * 16 + quad * 4 + r > qrow) s[nt][r] = -1e30f;
    }

    // P = exp2(s) (Q pre-scaled by log2e); pack to 16x16x16 A-frags via v_perm
    s16x4 pf[4];
    #pragma unroll
    for (int nt = 0; nt < 4; nt++) {
      float p0 = __ocml_native_exp2_f32(s[nt][0]);
      float p1 = __ocml_native_exp2_f32(s[nt][1]);
      float p2 = __ocml_native_exp2_f32(s[nt][2]);
      float p3 = __ocml_native_exp2_f32(s[nt][3]);
      union { s16x4 v; unsigned u[2]; } pk;
      pk.u[0] = __builtin_amdgcn_perm(__float_as_uint(p1), __float_as_uint(p0),
                                      0x07060302u);
      pk.u[1] = __builtin_amdgcn_perm(__float_as_uint(p3), __float_as_uint(p2),
                                      0x07060302u);
      pf[nt] = pk.v;
    }

    // V fragments: 8 conflict-free ds_read_b128 (4x4-interleaved layout:
    // chunk quad*2+r2 of a row holds kc=2*r2 (low 8B) and kc=2*r2+1 (high 8B))
    union { bf16x8 w; s16x4 hh[2]; } vv[2][4];
    #pragma unroll
    for (int r2 = 0; r2 < 2; r2++)
      #pragma unroll
      for (int dt = 0; dt < 4; dt++) {
        int row = dt * 16 + l15;
        vv[r2][dt].w = *reinterpret_cast<const bf16x8*>(
            (char*)Vs[cur] + row * 128 + (((quad * 2 + r2) ^ (row & 7)) << 4));
      }
    #pragma unroll
    for (int kc = 0; kc < 4; kc++) {
      accL = __builtin_amdgcn_mfma_f32_16x16x16bf16_1k(pf[kc], ones4, accL, 0, 0, 0);
      #pragma unroll
      for (int dt = 0; dt < 4; dt++)
        accO[dt] = __builtin_amdgcn_mfma_f32_16x16x16bf16_1k(
            pf[kc], vv[kc >> 1][dt].hh[kc & 1], accO[dt], 0, 0, 0);
    }
  }
  #undef SWZB

  // accL rows (quad*4+r) match accO rows — no cross-lane motion needed
  float inv[4];
  #pragma unroll
  for (int r = 0; r < 4; r++) inv[r] = 1.0f / accL[r];
  const int trow = qt * 64 + wave * 16 + quad * 4;
  #pragma unroll
  for (int dt = 0; dt < 4; dt++)
    #pragma unroll
    for (int r = 0; r < 4; r++)
      ctx[(b * 2048 + trow + r) * 1024 + h * 64 + dt * 16 + l15] =
          f2bf(accO[dt][r] * inv[r]);
}

// ---- out proj: out(8192x1024 fp32) = ctx @ wo^T + bo
// 128^2 tile, BK=64 fully-unrolled single-barrier dbuf (unchanged).
__global__ __launch_bounds__(256) void gemm_out_k(const u16* __restrict__ A,
                                                  const u16* __restrict__ Wt,
                                                  const float* __restrict__ bo,
                                                  float* __restrict__ out) {
  __shared__ u16 SM[32768];
  const int tid = threadIdx.x;
  const int wave = tid >> 6, lane = tid & 63;
  const int quad = lane >> 4, l15 = lane & 15;
  const int m0 = blockIdx.x * 128;
  const int n0 = blockIdx.y * 128;
  const int waveM = (wave >> 1) * 64, waveN = (wave & 1) * 64;

  const f32x4 fz = {0.f, 0.f, 0.f, 0.f};
  f32x4 acc[4][4];
  #pragma unroll
  for (int i = 0; i < 4; i++)
    #pragma unroll
    for (int j = 0; j < 4; j++) acc[i][j] = fz;

  const int lrow8 = lane >> 3, lchunk = lane & 7;
  const int gsw = (lchunk ^ lrow8) * 8;
  const u16* Agp[4];
  const u16* Bgp[4];
  #pragma unroll
  for (int i = 0; i < 4; i++) {
    Agp[i] = A + (m0 + i * 32 + wave * 8 + lrow8) * 1024 + gsw;
    Bgp[i] = Wt + (n0 + i * 32 + wave * 8 + lrow8) * 1024 + gsw;
  }

  #pragma unroll
  for (int i = 0; i < 4; i++) {
    gl_lds16(Agp[i], (char*)SM + i * 4096 + wave * 1024);
    gl_lds16(Bgp[i], (char*)SM + 32768 + i * 4096 + wave * 1024);
  }

  #pragma unroll
  for (int s = 0; s < 16; s++) {
    const int o = (s & 1) * 16384;
    __syncthreads();
    if (s < 15) {
      const int nxt = 16384 - o;
      const int koff = (s + 1) * 64;
      #pragma unroll
      for (int i = 0; i < 4; i++) {
        gl_lds16(Agp[i] + koff, (char*)SM + nxt + i * 4096 + wave * 1024);
        gl_lds16(Bgp[i] + koff, (char*)SM + 32768 + nxt + i * 4096 + wave * 1024);
      }
    }
    #pragma unroll
    for (int kk = 0; kk < 2; kk++) {
      bf16x8 af[4], bf[4];
      #pragma unroll
      for (int mi = 0; mi < 4; mi++)
        af[mi] = *reinterpret_cast<const bf16x8*>(
            (char*)SM + o + SWZ128(waveM + mi * 16 + l15, kk * 4 + quad));
      #pragma unroll
      for (int ni = 0; ni < 4; ni++)
        bf[ni] = *reinterpret_cast<const bf16x8*>(
            (char*)SM + 32768 + o + SWZ128(waveN + ni * 16 + l15, kk * 4 + quad));
      #pragma unroll
      for (int mi = 0; mi < 4; mi++)
        #pragma unroll
        for (int ni = 0; ni < 4; ni++)
          acc[mi][ni] = __builtin_amdgcn_mfma_f32_16x16x32_bf16(af[mi], bf[ni], acc[mi][ni], 0, 0, 0);
    }
  }
  float bias[4];
  #pragma unroll
  for (int ni = 0; ni < 4; ni++) bias[ni] = bo[n0 + waveN + ni * 16 + l15];
  #pragma unroll
  for (int mi = 0; mi < 4; mi++)
    #pragma unroll
    for (int r = 0; r < 4; r++) {
      int m = m0 + waveM + mi * 16 + quad * 4 + r;
      #pragma unroll
      for (int ni = 0; ni < 4; ni++) {
        int n = n0 + waveN + ni * 16 + l15;
        out[(size_t)m * 1024 + n] = acc[mi][ni][r] + bias[ni];
      }
    }
}

extern "C" void kernel_launch(void* const* d_in, const int* in_sizes, int n_in,
                              void* d_out, int out_size, void* d_ws, size_t ws_size,
                              hipStream_t stream) {
  const float* x  = (const float*)d_in[0];
  const float* wq = (const float*)d_in[1];
  const float* wk = (const float*)d_in[2];
  const float* wv = (const float*)d_in[3];
  const float* wo = (const float*)d_in[4];
  const float* bo = (const float*)d_in[5];
  float* out = (float*)d_out;
  char* ws = (char*)d_ws;

  u16* xb  = (u16*)(ws);                    // 16 MB (ctx reuses this)
  u16* wt  = (u16*)(ws + 16777216);         // 8 MB: wq^T|wk^T|wv^T|wo^T
  u16* qw  = (u16*)(ws + 25165824);         // 16 MB
  u16* kw  = (u16*)(ws + 41943040);         // 16 MB
  u16* vtw = (u16*)(ws + 58720256);         // 16 MB

  conv_x_k<<<8192, 256, 0, stream>>>(x, xb);
  conv_w_k<<<dim3(32, 32, 4), 256, 0, stream>>>(wq, wk, wv, wo, wt);
  gemm_qkv_k<<<dim3(32, 12), 512, 0, stream>>>(xb, wt, qw, kw, vtw);
  attn_k<<<dim3(64, 32), 256, 0, stream>>>(qw, kw, vtw, xb /*ctx*/);
  gemm_out_k<<<dim3(64, 8), 256, 0, stream>>>(xb, wt + 3 * 1024 * 1024, bo, out);
}

// Round 5
// 231.569 us; speedup vs baseline: 1.0648x; 1.0648x over previous
//
#include <hip/hip_runtime.h>
#include <stdint.h>

// MHA fused: B=4,T=2048,H=16,Dh=64,D=1024. fp32 in/out, bf16 MFMA internally.
// ws layout (bytes): [0,16M) x_bf16 (reused as ctx bf16 after QKV GEMM)
//                    [16M,24M) W^T bf16: wq|wk|wv|wo each 1024x1024 [n][k]
//                    [24M,40M) Q bf16 (B,H,T,Dh), pre-scaled by 0.125*log2(e)
//                    [40M,56M) K bf16 (B,H,T,Dh)
//                    [56M,72M) V^T bf16 (B,H,Dh,T), 4x4-interleaved j-blocks
// Total ws required: 75,497,472 bytes.
// R12: R11's counted-vmcnt regressed (66.4->71.5, sched_barrier pinning =
// m141 effect) -> revert to __syncthreads discipline. R10's real loss was
// the dispatch tail: 384 blocks @ 1 block/CU = 1.5 rounds (33% idle in
// round 2). Fix: BM=256 x BN=128 -> 768 blocks = 3 EXACT rounds, LDS 96KB,
// acc[4][4] (64 AGPR) per wave. Same proven sync/swizzle/epilogue structure.

typedef unsigned short u16;
typedef __bf16 bf16x8 __attribute__((ext_vector_type(8)));
typedef short s16x4 __attribute__((ext_vector_type(4)));
typedef float f32x4 __attribute__((ext_vector_type(4)));

extern "C" __device__ float __ocml_native_exp2_f32(float);

__device__ __forceinline__ u16 f2bf(float f) {
  union { float f; unsigned u; } v; v.f = f;
  return (u16)((v.u + 0x7fffu + ((v.u >> 16) & 1u)) >> 16);
}

__device__ __forceinline__ void gl_lds16(const void* g, void* l) {
  // 16B per lane, LDS dest = wave-uniform base + lane*16
  __builtin_amdgcn_global_load_lds((__attribute__((address_space(1))) void*)g,
                                   (__attribute__((address_space(3))) void*)l,
                                   16, 0, 0);
}

__global__ __launch_bounds__(256) void conv_x_k(const float* __restrict__ x,
                                                u16* __restrict__ xb) {
  int i = (blockIdx.x * 256 + threadIdx.x) * 4;
  float4 v = *reinterpret_cast<const float4*>(x + i);
  ushort4 o;
  o.x = f2bf(v.x); o.y = f2bf(v.y); o.z = f2bf(v.z); o.w = f2bf(v.w);
  *reinterpret_cast<ushort4*>(xb + i) = o;
}

// transpose 1024x1024 fp32 [k][n] -> bf16 [n][k]; z selects wq/wk/wv/wo
__global__ __launch_bounds__(256) void conv_w_k(const float* __restrict__ w0,
                                                const float* __restrict__ w1,
                                                const float* __restrict__ w2,
                                                const float* __restrict__ w3,
                                                u16* __restrict__ dst) {
  const float* src = blockIdx.z == 0 ? w0 : blockIdx.z == 1 ? w1
                   : blockIdx.z == 2 ? w2 : w3;
  u16* d = dst + (size_t)blockIdx.z * 1024 * 1024;
  __shared__ float tile[32][33];
  int n0 = blockIdx.x * 32, k0 = blockIdx.y * 32;
  int tx = threadIdx.x & 31, ty = threadIdx.x >> 5;  // 32 x 8
  #pragma unroll
  for (int r = 0; r < 32; r += 8)
    tile[ty + r][tx] = src[(k0 + ty + r) * 1024 + n0 + tx];
  __syncthreads();
  #pragma unroll
  for (int r = 0; r < 32; r += 8)
    d[(n0 + ty + r) * 1024 + k0 + tx] = f2bf(tile[tx][ty + r]);
}

// GEMM staging layout: rows of 64 u16 (128B), 8 x 16B chunks/row,
// phys chunk = logical chunk ^ (row&7) -> frag ds_read_b128 is 2-way (free).
#define SWZ128(row, chunk) ((row) * 128 + ((((chunk) ^ ((row) & 7))) << 4))

// ---- QKV GEMM: C(8192x1024 per proj) = xb @ W^T, epilogue scatters Q/K/V^T
// BM=256, BN=128, BK=64, 512 threads (8 waves, 4Mx2N, wave tile 64x64).
// LDS 96KB = 2 buffers x (A 32K | B 16K), alternating per K-tile.
// Grid 32x24 = 768 blocks @ 1 block/CU = 3 exact dispatch rounds (no tail).
// Per K-tile: __syncthreads (drains prev prefetch), issue 6 gl_lds16/wave
// for tile s+1 into other buffer, ds_read frags from current, 32 MFMAs.
__global__ __launch_bounds__(512, 2) void gemm_qkv_k(const u16* __restrict__ A,
                                                     const u16* __restrict__ Wt,
                                                     u16* __restrict__ qw,
                                                     u16* __restrict__ kw,
                                                     u16* __restrict__ vtw) {
  __shared__ u16 SM[49152];  // 96 KB; V-epilogue reuses first 64 KB
  const int tid = threadIdx.x;
  const int wave = tid >> 6, lane = tid & 63;
  const int quad = lane >> 4, l15 = lane & 15;
  const int m0 = blockIdx.x * 256;
  const int which = blockIdx.y >> 3;            // 0=Q 1=K 2=V
  const int n0 = (blockIdx.y & 7) * 128;
  const u16* Bt = Wt + which * (1024 * 1024);
  const int waveM = (wave >> 1) * 64, waveN = (wave & 1) * 64;

  const f32x4 fz = {0.f, 0.f, 0.f, 0.f};
  f32x4 acc[4][4];
  #pragma unroll
  for (int i = 0; i < 4; i++)
    #pragma unroll
    for (int j = 0; j < 4; j++) acc[i][j] = fz;

  // staging: per gl_lds16, wave covers rows {i*64 + wave*8 + r8},
  // r8 = lane>>3; lane&7 = 16B chunk slot (phys chunk = logical ^ r8).
  const int lrow8 = lane >> 3, lchunk = lane & 7;
  const int gsw = (lchunk ^ lrow8) * 8;  // pre-swizzled source chunk, elems
  const u16* Ag = A + (m0 + wave * 8 + lrow8) * 1024 + gsw;
  const u16* Bg = Bt + (n0 + wave * 8 + lrow8) * 1024 + gsw;

  auto stage = [&](int o, int ktv) {
    #pragma unroll
    for (int i = 0; i < 4; i++)   // A: 256 rows
      gl_lds16(Ag + (i * 64) * 1024 + ktv * 64,
               (char*)SM + o + i * 8192 + wave * 1024);
    #pragma unroll
    for (int i = 0; i < 2; i++)   // B: 128 rows
      gl_lds16(Bg + (i * 64) * 1024 + ktv * 64,
               (char*)SM + o + 32768 + i * 8192 + wave * 1024);
  };

  stage(0, 0);  // prologue: tile 0 -> buffer 0

  for (int s = 0; s < 16; s++) {
    const int o = (s & 1) * 49152;   // byte offset of current buffer
    __syncthreads();  // implicit vmcnt(0)+lgkmcnt(0): tile s visible,
                      // other buffer's readers (tile s-1) all done
    if (s < 15) stage(49152 - o, s + 1);  // in flight during compute of s

    bf16x8 bfr[4][2];
    #pragma unroll
    for (int nj = 0; nj < 4; nj++)
      #pragma unroll
      for (int kk = 0; kk < 2; kk++)
        bfr[nj][kk] = *reinterpret_cast<const bf16x8*>(
            (char*)SM + o + 32768 + SWZ128(waveN + nj * 16 + l15, kk * 4 + quad));

    bf16x8 af[4][2];
    #pragma unroll
    for (int mi = 0; mi < 4; mi++)
      #pragma unroll
      for (int kk = 0; kk < 2; kk++)
        af[mi][kk] = *reinterpret_cast<const bf16x8*>(
            (char*)SM + o + SWZ128(waveM + mi * 16 + l15, kk * 4 + quad));
    #pragma unroll
    for (int kk = 0; kk < 2; kk++)
      #pragma unroll
      for (int mi = 0; mi < 4; mi++)
        #pragma unroll
        for (int nj = 0; nj < 4; nj++)
          acc[mi][nj] = __builtin_amdgcn_mfma_f32_16x16x32_bf16(
              af[mi][kk], bfr[nj][kk], acc[mi][nj], 0, 0, 0);
  }

  if (which != 2) {  // Q/K: direct semi-coalesced u16 stores
    #pragma unroll
    for (int mi = 0; mi < 4; mi++) {
      #pragma unroll
      for (int r = 0; r < 4; r++) {
        int m = m0 + waveM + mi * 16 + quad * 4 + r;
        int b = m >> 11, t = m & 2047;
        #pragma unroll
        for (int nj = 0; nj < 4; nj++) {
          int n = n0 + waveN + nj * 16 + l15;
          int h = n >> 6, d = n & 63;
          float v = acc[mi][nj][r];
          // 0.125 * log2(e): attn exponentiates with native exp2
          if (which == 0) qw[((b * 16 + h) * 2048 + t) * 64 + d] = f2bf(v * 0.18033688f);
          else            kw[((b * 16 + h) * 2048 + t) * 64 + d] = f2bf(v);
        }
      }
    }
  } else {
    // V: transpose 256(t) x 128(n) tile in LDS (64KB of the 96KB), then
    // store coalesced with 4x4-interleaved j-blocks (per-64-t permutation:
    // stored unit u' = quad*4+kc holds j-group g=(u'&3)*4+(u'>>2)).
    __syncthreads();  // all waves done reading staging (loop fully drained)
    #pragma unroll
    for (int mi = 0; mi < 4; mi++)
      #pragma unroll
      for (int r = 0; r < 4; r++) {
        int ml = waveM + mi * 16 + quad * 4 + r;
        #pragma unroll
        for (int nj = 0; nj < 4; nj++) {
          int nl = waveN + nj * 16 + l15;
          // Ts[nl][ml]: 512B rows, 16B chunks of ml swizzled by nl&7
          int byte = nl * 512 + ((((ml >> 3) ^ (nl & 7))) << 4) + (ml & 7) * 2;
          *(u16*)((char*)SM + byte) = f2bf(acc[mi][nj][r]);
        }
      }
    __syncthreads();
    const int b = m0 >> 11, t0 = m0 & 2047;
    #pragma unroll
    for (int i = 0; i < 8; i++) {
      int cid = tid + 512 * i;        // 0..4095: (nl, 16B t-chunk)
      int nl = cid >> 5, tc = cid & 31;
      int jb = tc >> 3, cp = tc & 7;  // j-block within tile, chunk in block
      int gl = ((2 * cp) & 3) * 4 + ((2 * cp) >> 2);
      int gh = ((2 * cp + 1) & 3) * 4 + ((2 * cp + 1) >> 2);
      int ml0 = jb * 64 + gl * 4, ml1 = jb * 64 + gh * 4;
      s16x4 lo = *reinterpret_cast<const s16x4*>(
          (char*)SM + nl * 512 + (((ml0 >> 3) ^ (nl & 7)) << 4) + (ml0 & 7) * 2);
      s16x4 hi = *reinterpret_cast<const s16x4*>(
          (char*)SM + nl * 512 + (((ml1 >> 3) ^ (nl & 7)) << 4) + (ml1 & 7) * 2);
      union { s16x4 hh[2]; bf16x8 w; } uu;
      uu.hh[0] = lo; uu.hh[1] = hi;
      int n = n0 + nl;
      int h = n >> 6, d = n & 63;
      *reinterpret_cast<bf16x8*>(
          vtw + (((size_t)(b * 16 + h) * 64 + d) * 2048 + t0 + tc * 8)) = uu.w;
    }
  }
}

// ---- flash attention, causal. Br=Bc=64, one wave = 16 Q rows.
// P stays in registers (S^T C/D layout == 16x16x16 A-operand layout).
// native exp2 (log2e folded into Q scale); V tile 4x4-interleaved so V
// fragments are 8 conflict-free ds_read_b128 per iter.
__global__ __launch_bounds__(256) void attn_k(const u16* __restrict__ Q,
                                              const u16* __restrict__ K,
                                              const u16* __restrict__ Vt,
                                              u16* __restrict__ ctx) {
  __shared__ u16 Qs[64 * 64];
  __shared__ u16 Ks[2][64 * 64];
  __shared__ u16 Vs[2][64 * 64];    // V^T tile: [d][j-block interleaved]
  const int tid = threadIdx.x;
  const int wave = tid >> 6, lane = tid & 63;
  const int quad = lane >> 4, l15 = lane & 15;
  const int bh = blockIdx.x;
  const int qt = 31 - (int)blockIdx.y;          // big tiles dispatched first
  const int b = bh >> 4, h = bh & 15;

  const u16* Qg = Q + (bh * 2048 + qt * 64) * 64;
  const u16* Kg = K + bh * (2048 * 64);
  const u16* Vg = Vt + bh * (64 * 2048);

  const int lrow = tid >> 3;                       // 0..31
  const int lsw = ((tid & 7) ^ (lrow & 7)) * 8;    // swizzled chunk, elements

  // stage Q (swizzled): LDS slot tid*16, global chunk XORed by row&7
  gl_lds16(Qg + lrow * 64 + lsw, (char*)Qs + wave * 1024);
  gl_lds16(Qg + (32 + lrow) * 64 + lsw, (char*)Qs + wave * 1024 + 4096);
  // stage K/V tile 0
  {
    char* KsB = (char*)Ks[0] + wave * 1024;
    char* VsB = (char*)Vs[0] + wave * 1024;
    gl_lds16(Kg + lrow * 64 + lsw, KsB);
    gl_lds16(Kg + (32 + lrow) * 64 + lsw, KsB + 4096);
    gl_lds16(Vg + lrow * 2048 + lsw, VsB);
    gl_lds16(Vg + (32 + lrow) * 2048 + lsw, VsB + 4096);
  }

  const s16x4 ones4 = {(short)0x3F80, (short)0x3F80, (short)0x3F80, (short)0x3F80};
  const f32x4 fz = {0.f, 0.f, 0.f, 0.f};
  f32x4 accO[4];
  f32x4 accL = fz;
  #pragma unroll
  for (int dt = 0; dt < 4; dt++) accO[dt] = fz;
  bf16x8 qf[2];

  // swizzled fragment byte offset: row-major 64x64 u16, 16B chunk ^= row&7
  #define SWZB(row, chunk) ((row) * 128 + (((chunk) ^ ((row) & 7)) << 4))

  for (int j = 0; j <= qt; j++) {
    const int cur = j & 1;
    __syncthreads();  // drains vmcnt: tile j visible; buf cur^1 free to refill
    if (j < qt) {     // prefetch tile j+1 — stays in flight during compute j
      char* KsB = (char*)Ks[cur ^ 1] + wave * 1024;
      char* VsB = (char*)Vs[cur ^ 1] + wave * 1024;
      const int jr = (j + 1) * 64;
      gl_lds16(Kg + (jr + lrow) * 64 + lsw, KsB);
      gl_lds16(Kg + (jr + 32 + lrow) * 64 + lsw, KsB + 4096);
      gl_lds16(Vg + lrow * 2048 + jr + lsw, VsB);
      gl_lds16(Vg + (32 + lrow) * 2048 + jr + lsw, VsB + 4096);
    }
    if (j == 0) {
      #pragma unroll
      for (int kk = 0; kk < 2; kk++)
        qf[kk] = *reinterpret_cast<const bf16x8*>(
            (char*)Qs + SWZB(wave * 16 + l15, kk * 4 + quad));
    }

    // S^T tiles: mfma(A=kf, B=qf) -> lane holds S[q=l15][kcol=nt*16+quad*4+r]
    f32x4 s[4];
    #pragma unroll
    for (int nt = 0; nt < 4; nt++) s[nt] = fz;
    #pragma unroll
    for (int kk = 0; kk < 2; kk++)
      #pragma unroll
      for (int nt = 0; nt < 4; nt++) {
        bf16x8 kf = *reinterpret_cast<const bf16x8*>(
            (char*)Ks[cur] + SWZB(nt * 16 + l15, kk * 4 + quad));
        s[nt] = __builtin_amdgcn_mfma_f32_16x16x32_bf16(kf, qf[kk], s[nt], 0, 0, 0);
      }

    if (j == qt) {  // diagonal tile: mask kcol > qrow
      const int qrow = wave * 16 + l15;
      #pragma unroll
      for (int nt = 0; nt < 4; nt++)
        #pragma unroll
        for (int r = 0; r < 4; r++)
          if (nt * 16 + quad * 4 + r > qrow) s[nt][r] = -1e30f;
    }

    // P = exp2(s) (Q pre-scaled by log2e); pack to 16x16x16 A-frags via v_perm
    s16x4 pf[4];
    #pragma unroll
    for (int nt = 0; nt < 4; nt++) {
      float p0 = __ocml_native_exp2_f32(s[nt][0]);
      float p1 = __ocml_native_exp2_f32(s[nt][1]);
      float p2 = __ocml_native_exp2_f32(s[nt][2]);
      float p3 = __ocml_native_exp2_f32(s[nt][3]);
      union { s16x4 v; unsigned u[2]; } pk;
      pk.u[0] = __builtin_amdgcn_perm(__float_as_uint(p1), __float_as_uint(p0),
                                      0x07060302u);
      pk.u[1] = __builtin_amdgcn_perm(__float_as_uint(p3), __float_as_uint(p2),
                                      0x07060302u);
      pf[nt] = pk.v;
    }

    // V fragments: 8 conflict-free ds_read_b128 (4x4-interleaved layout:
    // chunk quad*2+r2 of a row holds kc=2*r2 (low 8B) and kc=2*r2+1 (high 8B))
    union { bf16x8 w; s16x4 hh[2]; } vv[2][4];
    #pragma unroll
    for (int r2 = 0; r2 < 2; r2++)
      #pragma unroll
      for (int dt = 0; dt < 4; dt++) {
        int row = dt * 16 + l15;
        vv[r2][dt].w = *reinterpret_cast<const bf16x8*>(
            (char*)Vs[cur] + row * 128 + (((quad * 2 + r2) ^ (row & 7)) << 4));
      }
    #pragma unroll
    for (int kc = 0; kc < 4; kc++) {
      accL = __builtin_amdgcn_mfma_f32_16x16x16bf16_1k(pf[kc], ones4, accL, 0, 0, 0);
      #pragma unroll
      for (int dt = 0; dt < 4; dt++)
        accO[dt] = __builtin_amdgcn_mfma_f32_16x16x16bf16_1k(
            pf[kc], vv[kc >> 1][dt].hh[kc & 1], accO[dt], 0, 0, 0);
    }
  }
  #undef SWZB

  // accL rows (quad*4+r) match accO rows — no cross-lane motion needed
  float inv[4];
  #pragma unroll
  for (int r = 0; r < 4; r++) inv[r] = 1.0f / accL[r];
  const int trow = qt * 64 + wave * 16 + quad * 4;
  #pragma unroll
  for (int dt = 0; dt < 4; dt++)
    #pragma unroll
    for (int r = 0; r < 4; r++)
      ctx[(b * 2048 + trow + r) * 1024 + h * 64 + dt * 16 + l15] =
          f2bf(accO[dt][r] * inv[r]);
}

// ---- out proj: out(8192x1024 fp32) = ctx @ wo^T + bo
// 128^2 tile, BK=64 fully-unrolled single-barrier dbuf (unchanged).
__global__ __launch_bounds__(256) void gemm_out_k(const u16* __restrict__ A,
                                                  const u16* __restrict__ Wt,
                                                  const float* __restrict__ bo,
                                                  float* __restrict__ out) {
  __shared__ u16 SM[32768];
  const int tid = threadIdx.x;
  const int wave = tid >> 6, lane = tid & 63;
  const int quad = lane >> 4, l15 = lane & 15;
  const int m0 = blockIdx.x * 128;
  const int n0 = blockIdx.y * 128;
  const int waveM = (wave >> 1) * 64, waveN = (wave & 1) * 64;

  const f32x4 fz = {0.f, 0.f, 0.f, 0.f};
  f32x4 acc[4][4];
  #pragma unroll
  for (int i = 0; i < 4; i++)
    #pragma unroll
    for (int j = 0; j < 4; j++) acc[i][j] = fz;

  const int lrow8 = lane >> 3, lchunk = lane & 7;
  const int gsw = (lchunk ^ lrow8) * 8;
  const u16* Agp[4];
  const u16* Bgp[4];
  #pragma unroll
  for (int i = 0; i < 4; i++) {
    Agp[i] = A + (m0 + i * 32 + wave * 8 + lrow8) * 1024 + gsw;
    Bgp[i] = Wt + (n0 + i * 32 + wave * 8 + lrow8) * 1024 + gsw;
  }

  #pragma unroll
  for (int i = 0; i < 4; i++) {
    gl_lds16(Agp[i], (char*)SM + i * 4096 + wave * 1024);
    gl_lds16(Bgp[i], (char*)SM + 32768 + i * 4096 + wave * 1024);
  }

  #pragma unroll
  for (int s = 0; s < 16; s++) {
    const int o = (s & 1) * 16384;
    __syncthreads();
    if (s < 15) {
      const int nxt = 16384 - o;
      const int koff = (s + 1) * 64;
      #pragma unroll
      for (int i = 0; i < 4; i++) {
        gl_lds16(Agp[i] + koff, (char*)SM + nxt + i * 4096 + wave * 1024);
        gl_lds16(Bgp[i] + koff, (char*)SM + 32768 + nxt + i * 4096 + wave * 1024);
      }
    }
    #pragma unroll
    for (int kk = 0; kk < 2; kk++) {
      bf16x8 af[4], bf[4];
      #pragma unroll
      for (int mi = 0; mi < 4; mi++)
        af[mi] = *reinterpret_cast<const bf16x8*>(
            (char*)SM + o + SWZ128(waveM + mi * 16 + l15, kk * 4 + quad));
      #pragma unroll
      for (int ni = 0; ni < 4; ni++)
        bf[ni] = *reinterpret_cast<const bf16x8*>(
            (char*)SM + 32768 + o + SWZ128(waveN + ni * 16 + l15, kk * 4 + quad));
      #pragma unroll
      for (int mi = 0; mi < 4; mi++)
        #pragma unroll
        for (int ni = 0; ni < 4; ni++)
          acc[mi][ni] = __builtin_amdgcn_mfma_f32_16x16x32_bf16(af[mi], bf[ni], acc[mi][ni], 0, 0, 0);
    }
  }
  float bias[4];
  #pragma unroll
  for (int ni = 0; ni < 4; ni++) bias[ni] = bo[n0 + waveN + ni * 16 + l15];
  #pragma unroll
  for (int mi = 0; mi < 4; mi++)
    #pragma unroll
    for (int r = 0; r < 4; r++) {
      int m = m0 + waveM + mi * 16 + quad * 4 + r;
      #pragma unroll
      for (int ni = 0; ni < 4; ni++) {
        int n = n0 + waveN + ni * 16 + l15;
        out[(size_t)m * 1024 + n] = acc[mi][ni][r] + bias[ni];
      }
    }
}

extern "C" void kernel_launch(void* const* d_in, const int* in_sizes, int n_in,
                              void* d_out, int out_size, void* d_ws, size_t ws_size,
                              hipStream_t stream) {
  const float* x  = (const float*)d_in[0];
  const float* wq = (const float*)d_in[1];
  const float* wk = (const float*)d_in[2];
  const float* wv = (const float*)d_in[3];
  const float* wo = (const float*)d_in[4];
  const float* bo = (const float*)d_in[5];
  float* out = (float*)d_out;
  char* ws = (char*)d_ws;

  u16* xb  = (u16*)(ws);                    // 16 MB (ctx reuses this)
  u16* wt  = (u16*)(ws + 16777216);         // 8 MB: wq^T|wk^T|wv^T|wo^T
  u16* qw  = (u16*)(ws + 25165824);         // 16 MB
  u16* kw  = (u16*)(ws + 41943040);         // 16 MB
  u16* vtw = (u16*)(ws + 58720256);         // 16 MB

  conv_x_k<<<8192, 256, 0, stream>>>(x, xb);
  conv_w_k<<<dim3(32, 32, 4), 256, 0, stream>>>(wq, wk, wv, wo, wt);
  gemm_qkv_k<<<dim3(32, 24), 512, 0, stream>>>(xb, wt, qw, kw, vtw);
  attn_k<<<dim3(64, 32), 256, 0, stream>>>(qw, kw, vtw, xb /*ctx*/);
  gemm_out_k<<<dim3(64, 8), 256, 0, stream>>>(xb, wt + 3 * 1024 * 1024, bo, out);
}